// Round 3
// baseline (280.178 us; speedup 1.0000x reference)
//
#include <hip/hip_runtime.h>
#include <stdint.h>

typedef __bf16 bf16;
typedef __bf16 bf16x8 __attribute__((ext_vector_type(8)));
typedef __bf16 bf16x4 __attribute__((ext_vector_type(4)));
typedef __bf16 bf16x2 __attribute__((ext_vector_type(2)));
typedef float  f32x4  __attribute__((ext_vector_type(4)));
typedef float  f32x16 __attribute__((ext_vector_type(16)));
typedef short  s16x4  __attribute__((ext_vector_type(4)));
typedef short  s16x8  __attribute__((ext_vector_type(8)));
typedef unsigned int u32x2 __attribute__((ext_vector_type(2)));
typedef unsigned int u32x4 __attribute__((ext_vector_type(4)));
typedef unsigned long long ull;

#define GLOAD16(gptr, lptr)                                                     \
  __builtin_amdgcn_global_load_lds(                                             \
      (const __attribute__((address_space(1))) void*)(gptr),                    \
      (__attribute__((address_space(3))) void*)(lptr), 16, 0, 0)

#define MFMA16(a, b, c) __builtin_amdgcn_mfma_f32_16x16x32_bf16((a), (b), (c), 0, 0, 0)
#define MFMA32(a, b, c) __builtin_amdgcn_mfma_f32_32x32x16_bf16((a), (b), (c), 0, 0, 0)

static constexpr int B_ = 2, L_ = 2048, NH_ = 16, DH_ = 64;
static constexpr float QSCALE = 0.18033688011112042f;  // 0.125 * log2(e)

// ---------- fused prep: maskbits | fp32->bf16 cvt | weight transpose ----------
__global__ __launch_bounds__(256) void k_prep(const float* __restrict__ q,
                                              const float* __restrict__ k,
                                              const float* __restrict__ v,
                                              const int* __restrict__ mask,
                                              const float* __restrict__ wq,
                                              const float* __restrict__ wk,
                                              const float* __restrict__ wv,
                                              const float* __restrict__ wo,
                                              bf16* __restrict__ X,
                                              bf16* __restrict__ Wt,
                                              ull* __restrict__ mb) {
  __shared__ float t[32][33];
  const int bid = blockIdx.x, tid = threadIdx.x;
  if (bid < 32768) {  // mask int32 -> packed bits
    int tt = bid * 256 + tid;
    ull bal = __ballot(mask[tt] != 0);
    if ((tid & 63) == 0) mb[tt >> 6] = bal;
  } else if (bid < 45056) {  // fp32 -> bf16 x4
    int u = bid - 32768;
    int z = u >> 12, x = u & 4095;
    const float* in = z == 0 ? q : (z == 1 ? k : v);
    bf16* out = X + (size_t)z * 4194304;
    int i = x * 256 + tid;
    const float4 f = ((const float4*)in)[i];
    bf16x4 o = {(bf16)f.x, (bf16)f.y, (bf16)f.z, (bf16)f.w};
    ((bf16x4*)out)[i] = o;
  } else {  // weight fp32 KxN -> bf16 NxK
    int u = bid - 45056;
    int z = u >> 10, rem = u & 1023;
    const float* in = z == 0 ? wq : (z == 1 ? wk : (z == 2 ? wv : wo));
    bf16* out = Wt + (size_t)z * 1048576;
    int bx = (rem & 31) * 32, by = (rem >> 5) * 32;
    int x = tid & 31, y = tid >> 5;
#pragma unroll
    for (int r = 0; r < 4; ++r)
      t[y + r * 8][x] = in[(size_t)(by + y + r * 8) * 1024 + bx + x];
    __syncthreads();
#pragma unroll
    for (int r = 0; r < 4; ++r)
      out[(size_t)(bx + y + r * 8) * 1024 + by + x] = (bf16)t[x][y + r * 8];
  }
}

// ---------- batched 3-proj GEMM: 128x128 tile, BK=32, 2-phase dbuf ----------
// z=0: Q scaled by QSCALE. z=2: V pre-tiled per raw-view head (faithful-bug reshape),
//   %8 key-grouping: h = l>>7, i = (l&127)*16 + (col>>6), d = col&63;
//   Vt[bh][((i>>3)*64 + d)*8 + (i&7)]  (one 16B load per PV B-frag in k_flash)
__global__ __launch_bounds__(256) void k_gemm3(const bf16* __restrict__ Xb,
                                               const bf16* __restrict__ Wb,
                                               const float* __restrict__ b0,
                                               const float* __restrict__ b1,
                                               const float* __restrict__ b2,
                                               bf16* __restrict__ Ob) {
  const int z = blockIdx.z;
  const bf16* A  = Xb + (size_t)z * 4194304;
  const bf16* Bt = Wb + (size_t)z * 1048576;
  const float* bias = z == 0 ? b0 : (z == 1 ? b1 : b2);
  bf16* C = Ob + (size_t)z * 4194304;
  const int m0 = blockIdx.y * 128, n0 = blockIdx.x * 128;
  __shared__ __align__(16) bf16 As[2 * 128 * 32];  // slot(r,c) = r*4 + (c ^ ((r>>1)&3))
  __shared__ __align__(16) bf16 Bs[2 * 128 * 32];
  const int tid = threadIdx.x, lane = tid & 63, w = tid >> 6, quad = lane >> 4, l15 = lane & 15;
  const int wm = (w & 1) * 64, wn = (w >> 1) * 64;
  f32x4 acc[4][4] = {};

#define G3STAGE(KT, BUF)                                                        \
  {                                                                             \
    const int kk_ = (KT) * 32;                                                  \
    _Pragma("unroll")                                                           \
    for (int i_ = 0; i_ < 2; ++i_) {                                            \
      int s_ = tid + i_ * 256;                                                  \
      int r_ = s_ >> 2, c_ = (s_ & 3) ^ ((r_ >> 1) & 3);                        \
      GLOAD16(A + (size_t)(m0 + r_) * 1024 + kk_ + c_ * 8, As + (BUF) * 4096 + s_ * 8);  \
      GLOAD16(Bt + (size_t)(n0 + r_) * 1024 + kk_ + c_ * 8, Bs + (BUF) * 4096 + s_ * 8); \
    }                                                                           \
  }

  G3STAGE(0, 0);
  for (int kt = 0; kt < 32; ++kt) {
    const int cur = kt & 1;
    __syncthreads();  // drains own stage(kt); all waves' buf[cur] visible
    if (kt + 1 < 32) G3STAGE(kt + 1, cur ^ 1);
    bf16x8 af[4], bb[4];
#pragma unroll
    for (int i = 0; i < 4; ++i) {
      int ra = wm + i * 16 + l15, rb = wn + i * 16 + l15;
      af[i] = *(const bf16x8*)(As + cur * 4096 + (ra * 4 + (quad ^ ((ra >> 1) & 3))) * 8);
      bb[i] = *(const bf16x8*)(Bs + cur * 4096 + (rb * 4 + (quad ^ ((rb >> 1) & 3))) * 8);
    }
#pragma unroll
    for (int mi = 0; mi < 4; ++mi)
#pragma unroll
      for (int ni = 0; ni < 4; ++ni)
        acc[mi][ni] = MFMA16(af[mi], bb[ni], acc[mi][ni]);
  }
#undef G3STAGE

  const float scale = (z == 0) ? QSCALE : 1.0f;
#pragma unroll
  for (int mi = 0; mi < 4; ++mi)
#pragma unroll
    for (int ni = 0; ni < 4; ++ni) {
      int row = m0 + wm + mi * 16 + quad * 4;
      int col = n0 + wn + ni * 16 + l15;
      float bz = bias[col];
      if (z == 2) {
        int b_ = row >> 11, l = row & 2047;
        int hh = l >> 7;
        int i0 = (l & 127) * 16 + (col >> 6);
        int d  = col & 63;
        bf16* dst = C + (size_t)(b_ * 16 + hh) * 131072;
#pragma unroll
        for (int r = 0; r < 4; ++r) {
          int iK = i0 + 16 * r;
          dst[((size_t)(iK >> 3) * 64 + d) * 8 + (iK & 7)] = (bf16)(acc[mi][ni][r] + bz);
        }
      } else {
#pragma unroll
        for (int r = 0; r < 4; ++r)
          C[(size_t)(row + r) * 1024 + col] = (bf16)((acc[mi][ni][r] + bz) * scale);
      }
    }
}

// ---------- output GEMM: 64x128 tile, 2-phase dbuf, fp32 out + bias ----------
__global__ __launch_bounds__(256) void k_gemmo(const bf16* __restrict__ A,
                                               const bf16* __restrict__ Bt,
                                               const float* __restrict__ bias,
                                               float* __restrict__ C) {
  const int m0 = blockIdx.y * 64, n0 = blockIdx.x * 128;
  __shared__ __align__(16) bf16 As[2 * 64 * 32];
  __shared__ __align__(16) bf16 Bs[2 * 128 * 32];
  const int tid = threadIdx.x, lane = tid & 63, w = tid >> 6, quad = lane >> 4, l15 = lane & 15;
  const int wn = w * 32;
  f32x4 acc[4][2] = {};

#define GOSTAGE(KT, BUF)                                                        \
  {                                                                             \
    const int kk_ = (KT) * 32;                                                  \
    {                                                                           \
      int r_ = tid >> 2, c_ = (tid & 3) ^ ((r_ >> 1) & 3);                      \
      GLOAD16(A + (size_t)(m0 + r_) * 1024 + kk_ + c_ * 8, As + (BUF) * 2048 + tid * 8); \
    }                                                                           \
    _Pragma("unroll")                                                           \
    for (int i_ = 0; i_ < 2; ++i_) {                                            \
      int s_ = tid + i_ * 256;                                                  \
      int r_ = s_ >> 2, c_ = (s_ & 3) ^ ((r_ >> 1) & 3);                        \
      GLOAD16(Bt + (size_t)(n0 + r_) * 1024 + kk_ + c_ * 8, Bs + (BUF) * 4096 + s_ * 8); \
    }                                                                           \
  }

  GOSTAGE(0, 0);
  for (int kt = 0; kt < 32; ++kt) {
    const int cur = kt & 1;
    __syncthreads();
    if (kt + 1 < 32) GOSTAGE(kt + 1, cur ^ 1);
    bf16x8 af[4], bb[2];
#pragma unroll
    for (int i = 0; i < 4; ++i) {
      int ra = i * 16 + l15;
      af[i] = *(const bf16x8*)(As + cur * 2048 + (ra * 4 + (quad ^ ((ra >> 1) & 3))) * 8);
    }
#pragma unroll
    for (int i = 0; i < 2; ++i) {
      int rb = wn + i * 16 + l15;
      bb[i] = *(const bf16x8*)(Bs + cur * 4096 + (rb * 4 + (quad ^ ((rb >> 1) & 3))) * 8);
    }
#pragma unroll
    for (int mi = 0; mi < 4; ++mi)
#pragma unroll
      for (int ni = 0; ni < 2; ++ni)
        acc[mi][ni] = MFMA16(af[mi], bb[ni], acc[mi][ni]);
  }
#undef GOSTAGE

#pragma unroll
  for (int mi = 0; mi < 4; ++mi)
#pragma unroll
    for (int ni = 0; ni < 2; ++ni) {
      int row = m0 + mi * 16 + quad * 4;
      int col = n0 + wn + ni * 16 + l15;
      float bz = bias[col];
#pragma unroll
      for (int r = 0; r < 4; ++r)
        C[(size_t)(row + r) * 1024 + col] = acc[mi][ni][r] + bz;
    }
}

static __device__ __forceinline__ unsigned pack2(float a, float b) {
  bf16x2 t = {(bf16)a, (bf16)b};
  return __builtin_bit_cast(unsigned, t);
}

// One kt step: V + mask word from GLOBAL (regs), K from LDS.
static __device__ __forceinline__ void flash_step(
    const bf16* __restrict__ Kc, const bf16* __restrict__ Vg, ull word,
    bf16x8 qf0, bf16x8 qf1, bf16x8 qf2, bf16x8 qf3, bf16x8 ones8,
    int hi, int l31, int kh, int vo0, int vo1, int vo2, int vo3,
    f32x16& accO0, f32x16& accO1, f32x16& accL) {
  // V frags straight from pre-tiled global (coalesced 16B/lane, L2-resident)
  bf16x8 v0 = *(const bf16x8*)(Vg + vo0);
  bf16x8 v1 = *(const bf16x8*)(Vg + vo1);
  bf16x8 v2 = *(const bf16x8*)(Vg + vo2);
  bf16x8 v3 = *(const bf16x8*)(Vg + vo3);

  // St = K Q^T (C: col=q=l31, row=key_rel=(reg&3)+8*(reg>>2)+4*hi)
  const int keyq = kh * 32 + l31;
  f32x16 st = {};
  __builtin_amdgcn_s_setprio(1);
#pragma unroll
  for (int ks = 0; ks < 4; ++ks) {
    bf16x8 kf = *(const bf16x8*)(Kc + (keyq * 8 + ((ks * 2 + hi) ^ (keyq & 7))) * 8);
    bf16x8 qf = ks == 0 ? qf0 : (ks == 1 ? qf1 : (ks == 2 ? qf2 : qf3));
    st = MFMA32(kf, qf, st);
  }
  __builtin_amdgcn_s_setprio(0);

  // mask + exp2
  const unsigned w32 = (unsigned)(word >> (kh * 32 + 4 * hi));
#pragma unroll
  for (int r = 0; r < 16; ++r) {
    const int bit = (r >> 2) * 8 + (r & 3);
    st[r] = (w32 >> bit) & 1u ? __builtin_amdgcn_exp2f(st[r]) : 0.f;
  }

  // pack P pairs + permlane32_swap -> PV A-frags (k = hi*8 + j)
  bf16x8 af0, af1;
  {
    unsigned c0 = pack2(st[0], st[1]);
    unsigned c1 = pack2(st[2], st[3]);
    unsigned c2 = pack2(st[4], st[5]);
    unsigned c3 = pack2(st[6], st[7]);
    u32x2 s0 = __builtin_amdgcn_permlane32_swap(c0, c2, false, false);
    u32x2 s1 = __builtin_amdgcn_permlane32_swap(c1, c3, false, false);
    u32x4 a4 = {s0.x, s1.x, s0.y, s1.y};
    af0 = __builtin_bit_cast(bf16x8, a4);
    c0 = pack2(st[8], st[9]);
    c1 = pack2(st[10], st[11]);
    c2 = pack2(st[12], st[13]);
    c3 = pack2(st[14], st[15]);
    s0 = __builtin_amdgcn_permlane32_swap(c0, c2, false, false);
    s1 = __builtin_amdgcn_permlane32_swap(c1, c3, false, false);
    u32x4 b4 = {s0.x, s1.x, s0.y, s1.y};
    af1 = __builtin_bit_cast(bf16x8, b4);
  }

  __builtin_amdgcn_s_setprio(1);
  accL  = MFMA32(af0, ones8, accL);
  accL  = MFMA32(af1, ones8, accL);
  accO0 = MFMA32(af0, v0, accO0);
  accO1 = MFMA32(af0, v1, accO1);
  accO0 = MFMA32(af1, v2, accO0);
  accO1 = MFMA32(af1, v3, accO1);
  __builtin_amdgcn_s_setprio(0);
}

// ---------- flash attention, 32x32x16, group-of-2 barriers ----------
// 512 thr = 8 waves = (key-half kh x q-quarter qq); q-tile 128.
// K: LDS 4 slots (2-tile groups, prefetch 1 group ahead) -> barrier per 2 kt.
// V: per-lane 16B register loads from %8-pre-tiled global (no LDS, no barrier dep).
// mask: per-lane 8B global loads (L1-sequential). Waves drift a full kt ->
// cross-wave MFMA/VALU overlap; setprio(1) biases MFMA-phase waves (T5).
__global__ __launch_bounds__(512, 4) void k_flash(const bf16* __restrict__ Qp,
                                                  const bf16* __restrict__ Kp,
                                                  const bf16* __restrict__ Vtp,
                                                  const ull* __restrict__ mb,
                                                  bf16* __restrict__ ctx) {
  const int b = blockIdx.z, h = blockIdx.y, q0 = blockIdx.x * 128;
  const size_t HEAD = 131072;
  const bf16* Q  = Qp  + ((size_t)b * NH_ + h) * HEAD;  // pre-scaled by QSCALE
  const bf16* K  = Kp  + ((size_t)b * NH_ + h) * HEAD;  // row-major [key][d]
  const bf16* Vt = Vtp + ((size_t)b * NH_ + h) * HEAD;  // pre-tiled [key>>3][d][key&7]
  const ull* mrow = mb + (size_t)b * L_ * 32;

  __shared__ __align__(16) unsigned char RAW[33280];
  bf16* Ksb = (bf16*)RAW;  // 4 slots x 4096 bf16; slot(key,cc), cc = c ^ (key&7)

  const int tid = threadIdx.x, lane = tid & 63, w = tid >> 6;
  const int hi = lane >> 5, l31 = lane & 31;
  const int kh = w & 1, qq = w >> 1;
  const size_t mwbase = (size_t)(q0 + qq * 32 + l31) * 32;
  const int vo0 = ((kh * 4 + hi) * 64 + l31) * 8;  // ks2=0, d=l31
  const int vo1 = vo0 + 256;                        // ks2=0, d=l31+32
  const int vo2 = vo0 + 1024;                       // ks2=1, d=l31
  const int vo3 = vo2 + 256;                        // ks2=1, d=l31+32

  // Q frags (B-operand: col=q=l31, k=d=ks*16+hi*8+j) straight from global
  bf16x8 qf0, qf1, qf2, qf3;
  {
    const bf16* qrow = Q + (size_t)(q0 + qq * 32 + l31) * 64 + hi * 8;
    qf0 = *(const bf16x8*)(qrow);
    qf1 = *(const bf16x8*)(qrow + 16);
    qf2 = *(const bf16x8*)(qrow + 32);
    qf3 = *(const bf16x8*)(qrow + 48);
  }

  // prologue: stage K tiles 0,1 into slots 0,1
  {
    int s = tid, key = s >> 3, c = (s & 7) ^ (key & 7);
    GLOAD16(K + (size_t)key * 64 + c * 8, Ksb + s * 8);
    GLOAD16(K + (size_t)(64 + key) * 64 + c * 8, Ksb + 4096 + s * 8);
  }
  __syncthreads();

  f32x16 accO0 = {}, accO1 = {}, accL = {};
  const s16x8 one8s = {0x3F80, 0x3F80, 0x3F80, 0x3F80, 0x3F80, 0x3F80, 0x3F80, 0x3F80};
  const bf16x8 ones8 = __builtin_bit_cast(bf16x8, one8s);

  for (int g = 0; g < 16; ++g) {
    const int cs = (g & 1) * 2;  // current slot pair
    // mask words for this group (global, L1-sequential per row)
    const ull word0 = mrow[mwbase + 2 * g];
    const ull word1 = mrow[mwbase + 2 * g + 1];
    // prefetch next group's K tiles into the other slot pair
    if (g + 1 < 16) {
      int s = tid, key = s >> 3, c = (s & 7) ^ (key & 7);
      const int ns = cs ^ 2;
      const size_t row0 = (size_t)(g + 1) * 128;  // first key row of next group
      GLOAD16(K + (row0 + key) * 64 + c * 8, Ksb + ns * 4096 + s * 8);
      GLOAD16(K + (row0 + 64 + key) * 64 + c * 8, Ksb + (ns + 1) * 4096 + s * 8);
    }
    flash_step(Ksb + cs * 4096, Vt + (size_t)(2 * g) * 4096, word0,
               qf0, qf1, qf2, qf3, ones8, hi, l31, kh, vo0, vo1, vo2, vo3,
               accO0, accO1, accL);
    flash_step(Ksb + (cs + 1) * 4096, Vt + (size_t)(2 * g + 1) * 4096, word1,
               qf0, qf1, qf2, qf3, ones8, hi, l31, kh, vo0, vo1, vo2, vo3,
               accO0, accO1, accL);
    __syncthreads();
  }

  // epilogue: combine kh halves through reused LDS, then normalize + store
  float* red  = (float*)RAW;            // [qq][32 q][64 d] = 32 KB
  float* redL = (float*)(RAW + 32768);  // [qq][32 q] = 512 B
  if (kh == 1) {
#pragma unroll
    for (int r = 0; r < 16; ++r) {
      const int qrel = (r & 3) + 8 * (r >> 2) + 4 * hi;
      red[qq * 2048 + qrel * 64 + l31]      = accO0[r];
      red[qq * 2048 + qrel * 64 + 32 + l31] = accO1[r];
      if (l31 == 0) redL[qq * 32 + qrel] = accL[r];
    }
  }
  __syncthreads();
  if (kh == 0) {
#pragma unroll
    for (int r = 0; r < 16; ++r) {
      const int qrel = (r & 3) + 8 * (r >> 2) + 4 * hi;
      const float ls = accL[r] + redL[qq * 32 + qrel];
      const float rl = 1.0f / ls;
      const float o0 = accO0[r] + red[qq * 2048 + qrel * 64 + l31];
      const float o1 = accO1[r] + red[qq * 2048 + qrel * 64 + 32 + l31];
      const int rowg = q0 + qq * 32 + qrel;
      ctx[((size_t)b * L_ + rowg) * 1024 + h * 64 + l31]      = (bf16)(o0 * rl);
      ctx[((size_t)b * L_ + rowg) * 1024 + h * 64 + 32 + l31] = (bf16)(o1 * rl);
    }
  }
}

extern "C" void kernel_launch(void* const* d_in, const int* in_sizes, int n_in,
                              void* d_out, int out_size, void* d_ws, size_t ws_size,
                              hipStream_t stream) {
  (void)in_sizes; (void)n_in; (void)out_size; (void)ws_size;
  const float* q    = (const float*)d_in[0];
  const float* k    = (const float*)d_in[1];
  const float* v    = (const float*)d_in[2];
  const int*   mask = (const int*)d_in[3];
  const float* Wq = (const float*)d_in[4];
  const float* bq = (const float*)d_in[5];
  const float* Wk = (const float*)d_in[6];
  const float* bk = (const float*)d_in[7];
  const float* Wv = (const float*)d_in[8];
  const float* bv = (const float*)d_in[9];
  const float* Wo = (const float*)d_in[10];
  const float* bo = (const float*)d_in[11];
  float* out = (float*)d_out;

  char* ws = (char*)d_ws;
  const size_t SX = (size_t)4096 * 1024 * 2;  // 8 MB
  const size_t SW = (size_t)1024 * 1024 * 2;  // 2 MB
  bf16* X   = (bf16*)(ws);                    // Xq|Xk|Xv
  bf16* Wt  = (bf16*)(ws + 3 * SX);           // Wqt|Wkt|Wvt|Wot
  bf16* QKV = (bf16*)(ws + 3 * SX + 4 * SW);  // Qp|Kp|Vt(pre-tiled)
  bf16* Qp  = QKV;
  bf16* Kp  = QKV + 4194304;
  bf16* Vtp = QKV + 2 * 4194304;
  bf16* Ctx = (bf16*)(ws + 6 * SX + 4 * SW);
  ull* mbits = (ull*)(ws + 7 * SX + 4 * SW);

  dim3 blk(256);
  k_prep<<<49152, blk, 0, stream>>>(q, k, v, mask, Wq, Wk, Wv, Wo, X, Wt, mbits);

  k_gemm3<<<dim3(8, 32, 3), blk, 0, stream>>>(X, Wt, bq, bk, bv, QKV);

  k_flash<<<dim3(16, NH_, B_), dim3(512), 0, stream>>>(Qp, Kp, Vtp, mbits, Ctx);

  k_gemmo<<<dim3(8, 64), blk, 0, stream>>>(Ctx, Wt + 3 * 1048576, bo, out);
}

// Round 4
// 275.850 us; speedup vs baseline: 1.0157x; 1.0157x over previous
//
#include <hip/hip_runtime.h>
#include <stdint.h>

typedef __bf16 bf16;
typedef __bf16 bf16x8 __attribute__((ext_vector_type(8)));
typedef __bf16 bf16x4 __attribute__((ext_vector_type(4)));
typedef __bf16 bf16x2 __attribute__((ext_vector_type(2)));
typedef float  f32x4  __attribute__((ext_vector_type(4)));
typedef float  f32x16 __attribute__((ext_vector_type(16)));
typedef short  s16x4  __attribute__((ext_vector_type(4)));
typedef short  s16x8  __attribute__((ext_vector_type(8)));
typedef unsigned int u32x2 __attribute__((ext_vector_type(2)));
typedef unsigned int u32x4 __attribute__((ext_vector_type(4)));
typedef unsigned long long ull;

#define GLOAD16(gptr, lptr)                                                     \
  __builtin_amdgcn_global_load_lds(                                             \
      (const __attribute__((address_space(1))) void*)(gptr),                    \
      (__attribute__((address_space(3))) void*)(lptr), 16, 0, 0)

#define MFMA16(a, b, c) __builtin_amdgcn_mfma_f32_16x16x32_bf16((a), (b), (c), 0, 0, 0)
#define MFMA32(a, b, c) __builtin_amdgcn_mfma_f32_32x32x16_bf16((a), (b), (c), 0, 0, 0)

static constexpr int B_ = 2, L_ = 2048, NH_ = 16, DH_ = 64;
static constexpr float QSCALE = 0.18033688011112042f;  // 0.125 * log2(e)

// ---------- fused prep: maskbits | fp32->bf16 cvt | weight transpose ----------
__global__ __launch_bounds__(256) void k_prep(const float* __restrict__ q,
                                              const float* __restrict__ k,
                                              const float* __restrict__ v,
                                              const int* __restrict__ mask,
                                              const float* __restrict__ wq,
                                              const float* __restrict__ wk,
                                              const float* __restrict__ wv,
                                              const float* __restrict__ wo,
                                              bf16* __restrict__ X,
                                              bf16* __restrict__ Wt,
                                              ull* __restrict__ mb) {
  __shared__ float t[32][33];
  const int bid = blockIdx.x, tid = threadIdx.x;
  if (bid < 32768) {  // mask int32 -> packed bits
    int tt = bid * 256 + tid;
    ull bal = __ballot(mask[tt] != 0);
    if ((tid & 63) == 0) mb[tt >> 6] = bal;
  } else if (bid < 45056) {  // fp32 -> bf16 x4
    int u = bid - 32768;
    int z = u >> 12, x = u & 4095;
    const float* in = z == 0 ? q : (z == 1 ? k : v);
    bf16* out = X + (size_t)z * 4194304;
    int i = x * 256 + tid;
    const float4 f = ((const float4*)in)[i];
    bf16x4 o = {(bf16)f.x, (bf16)f.y, (bf16)f.z, (bf16)f.w};
    ((bf16x4*)out)[i] = o;
  } else {  // weight fp32 KxN -> bf16 NxK
    int u = bid - 45056;
    int z = u >> 10, rem = u & 1023;
    const float* in = z == 0 ? wq : (z == 1 ? wk : (z == 2 ? wv : wo));
    bf16* out = Wt + (size_t)z * 1048576;
    int bx = (rem & 31) * 32, by = (rem >> 5) * 32;
    int x = tid & 31, y = tid >> 5;
#pragma unroll
    for (int r = 0; r < 4; ++r)
      t[y + r * 8][x] = in[(size_t)(by + y + r * 8) * 1024 + bx + x];
    __syncthreads();
#pragma unroll
    for (int r = 0; r < 4; ++r)
      out[(size_t)(bx + y + r * 8) * 1024 + by + x] = (bf16)t[x][y + r * 8];
  }
}

// ---------- batched 3-proj GEMM: 128x128 tile, BK=32 (m97 structure) ----------
// z=0: Q scaled by QSCALE. z=2: V pre-tiled per raw-view head (faithful-bug reshape),
//   %8 key-grouping: h = l>>7, i = (l&127)*16 + (col>>6), d = col&63;
//   Vt[bh][((i>>3)*64 + d)*8 + (i&7)]  (one 16B b128 frag per PV B-operand in k_flash)
__global__ __launch_bounds__(256) void k_gemm3(const bf16* __restrict__ Xb,
                                               const bf16* __restrict__ Wb,
                                               const float* __restrict__ b0,
                                               const float* __restrict__ b1,
                                               const float* __restrict__ b2,
                                               bf16* __restrict__ Ob) {
  const int z = blockIdx.z;
  const bf16* A  = Xb + (size_t)z * 4194304;
  const bf16* Bt = Wb + (size_t)z * 1048576;
  const float* bias = z == 0 ? b0 : (z == 1 ? b1 : b2);
  bf16* C = Ob + (size_t)z * 4194304;
  const int m0 = blockIdx.y * 128, n0 = blockIdx.x * 128;
  __shared__ __align__(16) bf16 As[128 * 32];  // slot(r,c) = r*4 + (c ^ ((r>>1)&3))
  __shared__ __align__(16) bf16 Bs[128 * 32];
  const int tid = threadIdx.x, lane = tid & 63, w = tid >> 6, quad = lane >> 4, l15 = lane & 15;
  const int wm = (w & 1) * 64, wn = (w >> 1) * 64;
  f32x4 acc[4][4] = {};
  for (int kt = 0; kt < 32; ++kt) {
    const int kk = kt * 32;
#pragma unroll
    for (int i = 0; i < 2; ++i) {
      int s = tid + i * 256;
      int r = s >> 2, c = (s & 3) ^ ((r >> 1) & 3);
      GLOAD16(A + (size_t)(m0 + r) * 1024 + kk + c * 8, As + s * 8);
      GLOAD16(Bt + (size_t)(n0 + r) * 1024 + kk + c * 8, Bs + s * 8);
    }
    __syncthreads();
    bf16x8 af[4], bb[4];
#pragma unroll
    for (int i = 0; i < 4; ++i) {
      int ra = wm + i * 16 + l15, rb = wn + i * 16 + l15;
      af[i] = *(const bf16x8*)(As + (ra * 4 + (quad ^ ((ra >> 1) & 3))) * 8);
      bb[i] = *(const bf16x8*)(Bs + (rb * 4 + (quad ^ ((rb >> 1) & 3))) * 8);
    }
#pragma unroll
    for (int mi = 0; mi < 4; ++mi)
#pragma unroll
      for (int ni = 0; ni < 4; ++ni)
        acc[mi][ni] = MFMA16(af[mi], bb[ni], acc[mi][ni]);
    __syncthreads();
  }
  const float scale = (z == 0) ? QSCALE : 1.0f;
#pragma unroll
  for (int mi = 0; mi < 4; ++mi)
#pragma unroll
    for (int ni = 0; ni < 4; ++ni) {
      int row = m0 + wm + mi * 16 + quad * 4;
      int col = n0 + wn + ni * 16 + l15;
      float bz = bias[col];
      if (z == 2) {
        int b_ = row >> 11, l = row & 2047;
        int hh = l >> 7;
        int i0 = (l & 127) * 16 + (col >> 6);
        int d  = col & 63;
        bf16* dst = C + (size_t)(b_ * 16 + hh) * 131072;
#pragma unroll
        for (int r = 0; r < 4; ++r) {
          int iK = i0 + 16 * r;
          dst[((size_t)(iK >> 3) * 64 + d) * 8 + (iK & 7)] = (bf16)(acc[mi][ni][r] + bz);
        }
      } else {
#pragma unroll
        for (int r = 0; r < 4; ++r)
          C[(size_t)(row + r) * 1024 + col] = (bf16)((acc[mi][ni][r] + bz) * scale);
      }
    }
}

// ---------- output GEMM: 64x128 tile, fp32 out + bias (m97 structure) ----------
__global__ __launch_bounds__(256) void k_gemmo(const bf16* __restrict__ A,
                                               const bf16* __restrict__ Bt,
                                               const float* __restrict__ bias,
                                               float* __restrict__ C) {
  const int m0 = blockIdx.y * 64, n0 = blockIdx.x * 128;
  __shared__ __align__(16) bf16 As[64 * 32];
  __shared__ __align__(16) bf16 Bs[128 * 32];
  const int tid = threadIdx.x, lane = tid & 63, w = tid >> 6, quad = lane >> 4, l15 = lane & 15;
  const int wn = w * 32;
  f32x4 acc[4][2] = {};
  for (int kt = 0; kt < 32; ++kt) {
    const int kk = kt * 32;
    {
      int r = tid >> 2, c = (tid & 3) ^ ((r >> 1) & 3);
      GLOAD16(A + (size_t)(m0 + r) * 1024 + kk + c * 8, As + tid * 8);
    }
#pragma unroll
    for (int i = 0; i < 2; ++i) {
      int s = tid + i * 256;
      int r = s >> 2, c = (s & 3) ^ ((r >> 1) & 3);
      GLOAD16(Bt + (size_t)(n0 + r) * 1024 + kk + c * 8, Bs + s * 8);
    }
    __syncthreads();
    bf16x8 af[4], bb[2];
#pragma unroll
    for (int i = 0; i < 4; ++i) {
      int ra = i * 16 + l15;
      af[i] = *(const bf16x8*)(As + (ra * 4 + (quad ^ ((ra >> 1) & 3))) * 8);
    }
#pragma unroll
    for (int i = 0; i < 2; ++i) {
      int rb = wn + i * 16 + l15;
      bb[i] = *(const bf16x8*)(Bs + (rb * 4 + (quad ^ ((rb >> 1) & 3))) * 8);
    }
#pragma unroll
    for (int mi = 0; mi < 4; ++mi)
#pragma unroll
      for (int ni = 0; ni < 2; ++ni)
        acc[mi][ni] = MFMA16(af[mi], bb[ni], acc[mi][ni]);
    __syncthreads();
  }
#pragma unroll
  for (int mi = 0; mi < 4; ++mi)
#pragma unroll
    for (int ni = 0; ni < 2; ++ni) {
      int row = m0 + mi * 16 + quad * 4;
      int col = n0 + wn + ni * 16 + l15;
      float bz = bias[col];
#pragma unroll
      for (int r = 0; r < 4; ++r)
        C[(size_t)(row + r) * 1024 + col] = acc[mi][ni][r] + bz;
    }
}

static __device__ __forceinline__ unsigned pack2(float a, float b) {
  bf16x2 t = {(bf16)a, (bf16)b};
  return __builtin_bit_cast(unsigned, t);
}

// One kt step: K and V frags from the given LDS slots, mask word from register.
static __device__ __forceinline__ void flash_step(
    const bf16* __restrict__ Kc, const bf16* __restrict__ Vc, ull word,
    const bf16x8 (&qf)[4], bf16x8 ones8,
    int hi, int keyq, int vo0, int vo1, int vo2, int vo3,
    f32x16& accO0, f32x16& accO1, f32x16& accL) {
  // V frags: single b128 LDS reads (tile pre-grouped %8 on key)
  bf16x8 v0 = *(const bf16x8*)(Vc + vo0);
  bf16x8 v1 = *(const bf16x8*)(Vc + vo1);
  bf16x8 v2 = *(const bf16x8*)(Vc + vo2);
  bf16x8 v3 = *(const bf16x8*)(Vc + vo3);

  // St = K Q^T (C: col=q, row=key_rel=(reg&3)+8*(reg>>2)+4*hi)
  f32x16 st = {};
  __builtin_amdgcn_s_setprio(1);
#pragma unroll
  for (int ks = 0; ks < 4; ++ks) {
    bf16x8 kf = *(const bf16x8*)(Kc + (keyq * 8 + ((ks * 2 + hi) ^ (keyq & 7))) * 8);
    st = MFMA32(kf, qf[ks], st);
  }
  __builtin_amdgcn_s_setprio(0);

  // mask + exp2
  const unsigned w32 = (unsigned)(word >> ((keyq & 32) + 4 * hi));
#pragma unroll
  for (int r = 0; r < 16; ++r) {
    const int bit = (r >> 2) * 8 + (r & 3);
    st[r] = (w32 >> bit) & 1u ? __builtin_amdgcn_exp2f(st[r]) : 0.f;
  }

  // pack P pairs + permlane32_swap -> PV A-frags (k = hi*8 + j)
  bf16x8 af0, af1;
  {
    unsigned c0 = pack2(st[0], st[1]);
    unsigned c1 = pack2(st[2], st[3]);
    unsigned c2 = pack2(st[4], st[5]);
    unsigned c3 = pack2(st[6], st[7]);
    u32x2 s0 = __builtin_amdgcn_permlane32_swap(c0, c2, false, false);
    u32x2 s1 = __builtin_amdgcn_permlane32_swap(c1, c3, false, false);
    u32x4 a4 = {s0.x, s1.x, s0.y, s1.y};
    af0 = __builtin_bit_cast(bf16x8, a4);
    c0 = pack2(st[8], st[9]);
    c1 = pack2(st[10], st[11]);
    c2 = pack2(st[12], st[13]);
    c3 = pack2(st[14], st[15]);
    s0 = __builtin_amdgcn_permlane32_swap(c0, c2, false, false);
    s1 = __builtin_amdgcn_permlane32_swap(c1, c3, false, false);
    u32x4 b4 = {s0.x, s1.x, s0.y, s1.y};
    af1 = __builtin_bit_cast(bf16x8, b4);
  }

  __builtin_amdgcn_s_setprio(1);
  accL  = MFMA32(af0, ones8, accL);
  accL  = MFMA32(af1, ones8, accL);
  accO0 = MFMA32(af0, v0, accO0);
  accO1 = MFMA32(af0, v1, accO1);
  accO0 = MFMA32(af1, v2, accO0);
  accO1 = MFMA32(af1, v3, accO1);
  __builtin_amdgcn_s_setprio(0);
}

// ---------- flash attention: counted-vmcnt 4-slot pipeline (T3/T4) ----------
// 512 thr = 8 waves = (key-half kh x q-quarter qq); q-tile 128.
// K,V: 4 LDS slots each (64 KB), prefetch depth 3. Per kt:
//   s_waitcnt vmcnt(N) + raw s_barrier (NO drain-to-0 in the loop),
//   stage(kt+3), compute(kt). Mask words preloaded 3 iters ahead in
//   rotating registers so compiler auto-waits never force a drain.
__global__ __launch_bounds__(512, 2) void k_flash(const bf16* __restrict__ Qp,
                                                  const bf16* __restrict__ Kp,
                                                  const bf16* __restrict__ Vtp,
                                                  const ull* __restrict__ mb,
                                                  bf16* __restrict__ ctx) {
  const int b = blockIdx.z, h = blockIdx.y, q0 = blockIdx.x * 128;
  const size_t HEAD = 131072;
  const bf16* Q  = Qp  + ((size_t)b * NH_ + h) * HEAD;  // pre-scaled by QSCALE
  const bf16* K  = Kp  + ((size_t)b * NH_ + h) * HEAD;  // row-major [key][d]
  const bf16* Vt = Vtp + ((size_t)b * NH_ + h) * HEAD;  // pre-tiled [key>>3][d][key&7]
  const ull* mrow = mb + (size_t)b * L_ * 32;

  __shared__ __align__(16) unsigned char RAW[65536];
  bf16* Ksb = (bf16*)RAW;             // 4 slots x 4096 bf16; slot(key,cc), cc=c^(key&7)
  bf16* Vsb = (bf16*)(RAW + 32768);   // 4 slots x 4096 bf16; straight pre-tiled copy

  const int tid = threadIdx.x, lane = tid & 63, w = tid >> 6;
  const int hi = lane >> 5, l31 = lane & 31;
  const int kh = w & 1, qq = w >> 1;
  const int keyq = kh * 32 + l31;
  const size_t mw = (size_t)(q0 + qq * 32 + l31) * 32;
  const int vo0 = ((kh * 4 + hi) * 64 + l31) * 8;  // ks2=0, d=l31
  const int vo1 = vo0 + 256;                        // ks2=0, d=l31+32
  const int vo2 = vo0 + 1024;                       // ks2=1, d=l31
  const int vo3 = vo2 + 256;                        // ks2=1, d=l31+32

  // Q frags (B-operand: col=q=l31, k=d=ks*16+hi*8+j) straight from global
  bf16x8 qf[4];
  {
    const bf16* qrow = Q + (size_t)(q0 + qq * 32 + l31) * 64 + hi * 8;
    qf[0] = *(const bf16x8*)(qrow);
    qf[1] = *(const bf16x8*)(qrow + 16);
    qf[2] = *(const bf16x8*)(qrow + 32);
    qf[3] = *(const bf16x8*)(qrow + 48);
  }

  // rotating mask-word registers (3 iterations ahead of consumption)
  ull wa = mrow[mw + 0], wb2 = mrow[mw + 1], wc = mrow[mw + 2], wd;

#define STAGE(T, SL)                                                            \
  {                                                                             \
    int s_ = tid, key_ = s_ >> 3, c_ = (s_ & 7) ^ (key_ & 7);                   \
    GLOAD16(K + ((size_t)(T) * 64 + key_) * 64 + c_ * 8, Ksb + (SL) * 4096 + s_ * 8); \
    GLOAD16(Vt + (size_t)(T) * 4096 + s_ * 8, Vsb + (SL) * 4096 + s_ * 8);      \
  }
#define WB(N) asm volatile("s_waitcnt vmcnt(" #N ")\n\ts_barrier" ::: "memory")
#define STEP(SL, WORD)                                                          \
  flash_step(Ksb + (SL) * 4096, Vsb + (SL) * 4096, (WORD), qf, ones8, hi, keyq, \
             vo0, vo1, vo2, vo3, accO0, accO1, accL)

  STAGE(0, 0);
  STAGE(1, 1);
  STAGE(2, 2);

  f32x16 accO0 = {}, accO1 = {}, accL = {};
  const s16x8 one8s = {0x3F80, 0x3F80, 0x3F80, 0x3F80, 0x3F80, 0x3F80, 0x3F80, 0x3F80};
  const bf16x8 ones8 = __builtin_bit_cast(bf16x8, one8s);

  // macro-iter 0 (exact prologue counts)
  WB(4); wd  = mrow[mw + 3]; STAGE(3, 3); STEP(0, wa);
  WB(5); wa  = mrow[mw + 4]; STAGE(4, 0); STEP(1, wb2);
  WB(6); wb2 = mrow[mw + 5]; STAGE(5, 1); STEP(2, wc);
  WB(6); wc  = mrow[mw + 6]; STAGE(6, 2); STEP(3, wd);
  // steady state
  for (int g = 1; g < 7; ++g) {
    const int kt0 = g * 4;
    WB(6); wd  = mrow[mw + kt0 + 3]; STAGE(kt0 + 3, 3); STEP(0, wa);
    WB(6); wa  = mrow[mw + kt0 + 4]; STAGE(kt0 + 4, 0); STEP(1, wb2);
    WB(6); wb2 = mrow[mw + kt0 + 5]; STAGE(kt0 + 5, 1); STEP(2, wc);
    WB(6); wc  = mrow[mw + kt0 + 6]; STAGE(kt0 + 6, 2); STEP(3, wd);
  }
  // tail (kt = 28..31, exact drain counts)
  WB(6); wd = mrow[mw + 31]; STAGE(31, 3); STEP(0, wa);
  WB(5); STEP(1, wb2);
  WB(3); STEP(2, wc);
  WB(0); STEP(3, wd);
#undef STEP
#undef WB
#undef STAGE

  __syncthreads();

  // epilogue: combine kh halves through reused LDS, then normalize + store
  float* red  = (float*)RAW;            // [qq][32 q][64 d] = 32 KB
  float* redL = (float*)(RAW + 32768);  // [qq][32 q] = 512 B
  if (kh == 1) {
#pragma unroll
    for (int r = 0; r < 16; ++r) {
      const int qrel = (r & 3) + 8 * (r >> 2) + 4 * hi;
      red[qq * 2048 + qrel * 64 + l31]      = accO0[r];
      red[qq * 2048 + qrel * 64 + 32 + l31] = accO1[r];
      if (l31 == 0) redL[qq * 32 + qrel] = accL[r];
    }
  }
  __syncthreads();
  if (kh == 0) {
#pragma unroll
    for (int r = 0; r < 16; ++r) {
      const int qrel = (r & 3) + 8 * (r >> 2) + 4 * hi;
      const float ls = accL[r] + redL[qq * 32 + qrel];
      const float rl = 1.0f / ls;
      const float o0 = accO0[r] + red[qq * 2048 + qrel * 64 + l31];
      const float o1 = accO1[r] + red[qq * 2048 + qrel * 64 + 32 + l31];
      const int rowg = q0 + qq * 32 + qrel;
      ctx[((size_t)b * L_ + rowg) * 1024 + h * 64 + l31]      = (bf16)(o0 * rl);
      ctx[((size_t)b * L_ + rowg) * 1024 + h * 64 + 32 + l31] = (bf16)(o1 * rl);
    }
  }
}

extern "C" void kernel_launch(void* const* d_in, const int* in_sizes, int n_in,
                              void* d_out, int out_size, void* d_ws, size_t ws_size,
                              hipStream_t stream) {
  (void)in_sizes; (void)n_in; (void)out_size; (void)ws_size;
  const float* q    = (const float*)d_in[0];
  const float* k    = (const float*)d_in[1];
  const float* v    = (const float*)d_in[2];
  const int*   mask = (const int*)d_in[3];
  const float* Wq = (const float*)d_in[4];
  const float* bq = (const float*)d_in[5];
  const float* Wk = (const float*)d_in[6];
  const float* bk = (const float*)d_in[7];
  const float* Wv = (const float*)d_in[8];
  const float* bv = (const float*)d_in[9];
  const float* Wo = (const float*)d_in[10];
  const float* bo = (const float*)d_in[11];
  float* out = (float*)d_out;

  char* ws = (char*)d_ws;
  const size_t SX = (size_t)4096 * 1024 * 2;  // 8 MB
  const size_t SW = (size_t)1024 * 1024 * 2;  // 2 MB
  bf16* X   = (bf16*)(ws);                    // Xq|Xk|Xv
  bf16* Wt  = (bf16*)(ws + 3 * SX);           // Wqt|Wkt|Wvt|Wot
  bf16* QKV = (bf16*)(ws + 3 * SX + 4 * SW);  // Qp|Kp|Vt(pre-tiled)
  bf16* Qp  = QKV;
  bf16* Kp  = QKV + 4194304;
  bf16* Vtp = QKV + 2 * 4194304;
  bf16* Ctx = (bf16*)(ws + 6 * SX + 4 * SW);
  ull* mbits = (ull*)(ws + 7 * SX + 4 * SW);

  dim3 blk(256);
  k_prep<<<49152, blk, 0, stream>>>(q, k, v, mask, Wq, Wk, Wv, Wo, X, Wt, mbits);

  k_gemm3<<<dim3(8, 32, 3), blk, 0, stream>>>(X, Wt, bq, bk, bv, QKV);

  k_flash<<<dim3(16, NH_, B_), dim3(512), 0, stream>>>(Qp, Kp, Vtp, mbits, Ctx);

  k_gemmo<<<dim3(8, 64), blk, 0, stream>>>(Ctx, Wt + 3 * 1048576, bo, out);
}

// Round 5
// 266.507 us; speedup vs baseline: 1.0513x; 1.0351x over previous
//
#include <hip/hip_runtime.h>
#include <stdint.h>

typedef __bf16 bf16;
typedef __bf16 bf16x8 __attribute__((ext_vector_type(8)));
typedef __bf16 bf16x4 __attribute__((ext_vector_type(4)));
typedef __bf16 bf16x2 __attribute__((ext_vector_type(2)));
typedef float  f32x4  __attribute__((ext_vector_type(4)));
typedef float  f32x16 __attribute__((ext_vector_type(16)));
typedef short  s16x4  __attribute__((ext_vector_type(4)));
typedef short  s16x8  __attribute__((ext_vector_type(8)));
typedef unsigned int u32x2 __attribute__((ext_vector_type(2)));
typedef unsigned int u32x4 __attribute__((ext_vector_type(4)));
typedef unsigned long long ull;

#define GLOAD16(gptr, lptr)                                                     \
  __builtin_amdgcn_global_load_lds(                                             \
      (const __attribute__((address_space(1))) void*)(gptr),                    \
      (__attribute__((address_space(3))) void*)(lptr), 16, 0, 0)

#define MFMA16(a, b, c) __builtin_amdgcn_mfma_f32_16x16x32_bf16((a), (b), (c), 0, 0, 0)
#define MFMA32(a, b, c) __builtin_amdgcn_mfma_f32_32x32x16_bf16((a), (b), (c), 0, 0, 0)

static constexpr int B_ = 2, L_ = 2048, NH_ = 16, DH_ = 64;
static constexpr float QSCALE = 0.18033688011112042f;  // 0.125 * log2(e)

// ---------- fused prep (grid-stride, 5120 blocks): maskbits | cvt | transpose ----------
__global__ __launch_bounds__(256) void k_prep(const float* __restrict__ q,
                                              const float* __restrict__ k,
                                              const float* __restrict__ v,
                                              const int* __restrict__ mask,
                                              const float* __restrict__ wq,
                                              const float* __restrict__ wk,
                                              const float* __restrict__ wv,
                                              const float* __restrict__ wo,
                                              bf16* __restrict__ X,
                                              bf16* __restrict__ Wt,
                                              ull* __restrict__ mb) {
  __shared__ float t[32][33];
  const int bid = blockIdx.x, tid = threadIdx.x;
  if (bid < 2048) {  // mask int32 -> packed bits: 16 chunks/block
#pragma unroll
    for (int it = 0; it < 16; ++it) {
      int tt = (bid * 16 + it) * 256 + tid;
      ull bal = __ballot(mask[tt] != 0);
      if ((tid & 63) == 0) mb[tt >> 6] = bal;
    }
  } else if (bid < 4096) {  // fp32 -> bf16 x4: 6 chunks/block
    const int u0 = (bid - 2048) * 6;
#pragma unroll
    for (int it = 0; it < 6; ++it) {
      int u = u0 + it;
      int z = u >> 12, x = u & 4095;
      const float* in = z == 0 ? q : (z == 1 ? k : v);
      bf16* out = X + (size_t)z * 4194304;
      int i = x * 256 + tid;
      const float4 f = ((const float4*)in)[i];
      bf16x4 o = {(bf16)f.x, (bf16)f.y, (bf16)f.z, (bf16)f.w};
      ((bf16x4*)out)[i] = o;
    }
  } else {  // weight fp32 KxN -> bf16 NxK: 4 tiles/block
    const int t0 = (bid - 4096) * 4;
    for (int it = 0; it < 4; ++it) {
      int u = t0 + it;
      int z = u >> 10, rem = u & 1023;
      const float* in = z == 0 ? wq : (z == 1 ? wk : (z == 2 ? wv : wo));
      bf16* out = Wt + (size_t)z * 1048576;
      int bx = (rem & 31) * 32, by = (rem >> 5) * 32;
      int x = tid & 31, y = tid >> 5;
#pragma unroll
      for (int r = 0; r < 4; ++r)
        t[y + r * 8][x] = in[(size_t)(by + y + r * 8) * 1024 + bx + x];
      __syncthreads();
#pragma unroll
      for (int r = 0; r < 4; ++r)
        out[(size_t)(bx + y + r * 8) * 1024 + by + x] = (bf16)t[x][y + r * 8];
      __syncthreads();  // WAR on t before next tile
    }
  }
}

// ---------- batched 3-proj GEMM: 128x128 tile, BK=32 (m97 structure) ----------
// z=0: Q scaled by QSCALE. z=2: V pre-tiled per raw-view head (faithful-bug reshape),
//   %8 key-grouping: h = l>>7, i = (l&127)*16 + (col>>6), d = col&63;
//   Vt[bh][((i>>3)*64 + d)*8 + (i&7)]  (one 16B b128 frag per PV B-operand in k_flash)
__global__ __launch_bounds__(256) void k_gemm3(const bf16* __restrict__ Xb,
                                               const bf16* __restrict__ Wb,
                                               const float* __restrict__ b0,
                                               const float* __restrict__ b1,
                                               const float* __restrict__ b2,
                                               bf16* __restrict__ Ob) {
  const int z = blockIdx.z;
  const bf16* A  = Xb + (size_t)z * 4194304;
  const bf16* Bt = Wb + (size_t)z * 1048576;
  const float* bias = z == 0 ? b0 : (z == 1 ? b1 : b2);
  bf16* C = Ob + (size_t)z * 4194304;
  const int m0 = blockIdx.y * 128, n0 = blockIdx.x * 128;
  __shared__ __align__(16) bf16 As[128 * 32];  // slot(r,c) = r*4 + (c ^ ((r>>1)&3))
  __shared__ __align__(16) bf16 Bs[128 * 32];
  const int tid = threadIdx.x, lane = tid & 63, w = tid >> 6, quad = lane >> 4, l15 = lane & 15;
  const int wm = (w & 1) * 64, wn = (w >> 1) * 64;
  f32x4 acc[4][4] = {};
  for (int kt = 0; kt < 32; ++kt) {
    const int kk = kt * 32;
#pragma unroll
    for (int i = 0; i < 2; ++i) {
      int s = tid + i * 256;
      int r = s >> 2, c = (s & 3) ^ ((r >> 1) & 3);
      GLOAD16(A + (size_t)(m0 + r) * 1024 + kk + c * 8, As + s * 8);
      GLOAD16(Bt + (size_t)(n0 + r) * 1024 + kk + c * 8, Bs + s * 8);
    }
    __syncthreads();
    bf16x8 af[4], bb[4];
#pragma unroll
    for (int i = 0; i < 4; ++i) {
      int ra = wm + i * 16 + l15, rb = wn + i * 16 + l15;
      af[i] = *(const bf16x8*)(As + (ra * 4 + (quad ^ ((ra >> 1) & 3))) * 8);
      bb[i] = *(const bf16x8*)(Bs + (rb * 4 + (quad ^ ((rb >> 1) & 3))) * 8);
    }
#pragma unroll
    for (int mi = 0; mi < 4; ++mi)
#pragma unroll
      for (int ni = 0; ni < 4; ++ni)
        acc[mi][ni] = MFMA16(af[mi], bb[ni], acc[mi][ni]);
    __syncthreads();
  }
  const float scale = (z == 0) ? QSCALE : 1.0f;
#pragma unroll
  for (int mi = 0; mi < 4; ++mi)
#pragma unroll
    for (int ni = 0; ni < 4; ++ni) {
      int row = m0 + wm + mi * 16 + quad * 4;
      int col = n0 + wn + ni * 16 + l15;
      float bz = bias[col];
      if (z == 2) {
        int b_ = row >> 11, l = row & 2047;
        int hh = l >> 7;
        int i0 = (l & 127) * 16 + (col >> 6);
        int d  = col & 63;
        bf16* dst = C + (size_t)(b_ * 16 + hh) * 131072;
#pragma unroll
        for (int r = 0; r < 4; ++r) {
          int iK = i0 + 16 * r;
          dst[((size_t)(iK >> 3) * 64 + d) * 8 + (iK & 7)] = (bf16)(acc[mi][ni][r] + bz);
        }
      } else {
#pragma unroll
        for (int r = 0; r < 4; ++r)
          C[(size_t)(row + r) * 1024 + col] = (bf16)((acc[mi][ni][r] + bz) * scale);
      }
    }
}

// ---------- output GEMM: 64x128 tile, fp32 out + bias (m97 structure) ----------
__global__ __launch_bounds__(256) void k_gemmo(const bf16* __restrict__ A,
                                               const bf16* __restrict__ Bt,
                                               const float* __restrict__ bias,
                                               float* __restrict__ C) {
  const int m0 = blockIdx.y * 64, n0 = blockIdx.x * 128;
  __shared__ __align__(16) bf16 As[64 * 32];
  __shared__ __align__(16) bf16 Bs[128 * 32];
  const int tid = threadIdx.x, lane = tid & 63, w = tid >> 6, quad = lane >> 4, l15 = lane & 15;
  const int wn = w * 32;
  f32x4 acc[4][2] = {};
  for (int kt = 0; kt < 32; ++kt) {
    const int kk = kt * 32;
    {
      int r = tid >> 2, c = (tid & 3) ^ ((r >> 1) & 3);
      GLOAD16(A + (size_t)(m0 + r) * 1024 + kk + c * 8, As + tid * 8);
    }
#pragma unroll
    for (int i = 0; i < 2; ++i) {
      int s = tid + i * 256;
      int r = s >> 2, c = (s & 3) ^ ((r >> 1) & 3);
      GLOAD16(Bt + (size_t)(n0 + r) * 1024 + kk + c * 8, Bs + s * 8);
    }
    __syncthreads();
    bf16x8 af[4], bb[2];
#pragma unroll
    for (int i = 0; i < 4; ++i) {
      int ra = i * 16 + l15;
      af[i] = *(const bf16x8*)(As + (ra * 4 + (quad ^ ((ra >> 1) & 3))) * 8);
    }
#pragma unroll
    for (int i = 0; i < 2; ++i) {
      int rb = wn + i * 16 + l15;
      bb[i] = *(const bf16x8*)(Bs + (rb * 4 + (quad ^ ((rb >> 1) & 3))) * 8);
    }
#pragma unroll
    for (int mi = 0; mi < 4; ++mi)
#pragma unroll
      for (int ni = 0; ni < 2; ++ni)
        acc[mi][ni] = MFMA16(af[mi], bb[ni], acc[mi][ni]);
    __syncthreads();
  }
#pragma unroll
  for (int mi = 0; mi < 4; ++mi)
#pragma unroll
    for (int ni = 0; ni < 2; ++ni) {
      int row = m0 + mi * 16 + quad * 4;
      int col = n0 + wn + ni * 16 + l15;
      float bz = bias[col];
#pragma unroll
      for (int r = 0; r < 4; ++r)
        C[(size_t)(row + r) * 1024 + col] = acc[mi][ni][r] + bz;
    }
}

static __device__ __forceinline__ unsigned pack2(float a, float b) {
  bf16x2 t = {(bf16)a, (bf16)b};
  return __builtin_bit_cast(unsigned, t);
}

// One kt step: K and V frags from LDS, mask word from register.
static __device__ __forceinline__ void flash_step(
    const bf16* __restrict__ Kc, const bf16* __restrict__ Vc, ull word,
    const bf16x8 (&qf)[4], bf16x8 ones8,
    int hi, int keyq, int swz, int vo0, int vo1, int vo2, int vo3,
    f32x16& accO0, f32x16& accO1, f32x16& accL) {
  // V frags: single b128 LDS reads (tile pre-grouped %8 on key)
  bf16x8 v0 = *(const bf16x8*)(Vc + vo0);
  bf16x8 v1 = *(const bf16x8*)(Vc + vo1);
  bf16x8 v2 = *(const bf16x8*)(Vc + vo2);
  bf16x8 v3 = *(const bf16x8*)(Vc + vo3);

  // St = K Q^T (C: col=q, row=key_rel=(reg&3)+8*(reg>>2)+4*hi)
  f32x16 st = {};
  __builtin_amdgcn_s_setprio(1);
#pragma unroll
  for (int ks = 0; ks < 4; ++ks) {
    bf16x8 kf = *(const bf16x8*)(Kc + (keyq * 8 + ((ks * 2 + hi) ^ swz)) * 8);
    st = MFMA32(kf, qf[ks], st);
  }
  __builtin_amdgcn_s_setprio(0);

  // mask + exp2
  const unsigned w32 = (unsigned)(word >> ((keyq & 32) + 4 * hi));
#pragma unroll
  for (int r = 0; r < 16; ++r) {
    const int bit = (r >> 2) * 8 + (r & 3);
    st[r] = (w32 >> bit) & 1u ? __builtin_amdgcn_exp2f(st[r]) : 0.f;
  }

  // pack P pairs + permlane32_swap -> PV A-frags (k = hi*8 + j)
  bf16x8 af0, af1;
  {
    unsigned c0 = pack2(st[0], st[1]);
    unsigned c1 = pack2(st[2], st[3]);
    unsigned c2 = pack2(st[4], st[5]);
    unsigned c3 = pack2(st[6], st[7]);
    u32x2 s0 = __builtin_amdgcn_permlane32_swap(c0, c2, false, false);
    u32x2 s1 = __builtin_amdgcn_permlane32_swap(c1, c3, false, false);
    u32x4 a4 = {s0.x, s1.x, s0.y, s1.y};
    af0 = __builtin_bit_cast(bf16x8, a4);
    c0 = pack2(st[8], st[9]);
    c1 = pack2(st[10], st[11]);
    c2 = pack2(st[12], st[13]);
    c3 = pack2(st[14], st[15]);
    s0 = __builtin_amdgcn_permlane32_swap(c0, c2, false, false);
    s1 = __builtin_amdgcn_permlane32_swap(c1, c3, false, false);
    u32x4 b4 = {s0.x, s1.x, s0.y, s1.y};
    af1 = __builtin_bit_cast(bf16x8, b4);
  }

  __builtin_amdgcn_s_setprio(1);
  accL  = MFMA32(af0, ones8, accL);
  accL  = MFMA32(af1, ones8, accL);
  accO0 = MFMA32(af0, v0, accO0);
  accO1 = MFMA32(af0, v1, accO1);
  accO0 = MFMA32(af1, v2, accO0);
  accO1 = MFMA32(af1, v3, accO1);
  __builtin_amdgcn_s_setprio(0);
}

// ---------- flash attention: q-tile 64, 256 thr (4 waves = kh x qq), 4 blocks/CU ----------
// R2 structure (best measured: syncthreads dbuf), two changes:
//  1. q-tile 128->64: grid 1024 blocks -> 4 blocks/CU (was 2). Blocks are
//     independent barrier domains -> cross-block MFMA/VALU overlap (m114).
//  2. K swizzle S(key)=(key^(key>>3))&7 (was key&7): kills the 4-way bank
//     conflict between lanes with equal key&7 (keyq, +8, +16, +24).
__global__ __launch_bounds__(256, 4) void k_flash(const bf16* __restrict__ Qp,
                                                  const bf16* __restrict__ Kp,
                                                  const bf16* __restrict__ Vtp,
                                                  const ull* __restrict__ mb,
                                                  bf16* __restrict__ ctx) {
  const int b = blockIdx.z, h = blockIdx.y, q0 = blockIdx.x * 64;
  const size_t HEAD = 131072;
  const bf16* Q  = Qp  + ((size_t)b * NH_ + h) * HEAD;  // pre-scaled by QSCALE
  const bf16* K  = Kp  + ((size_t)b * NH_ + h) * HEAD;  // row-major [key][d]
  const bf16* Vt = Vtp + ((size_t)b * NH_ + h) * HEAD;  // pre-tiled [key>>3][d][key&7]
  const ull* mrow = mb + (size_t)b * L_ * 32;

  // LDS: Ks 2x8KB | Vs 2x8KB | Ms 2x1KB = 34816 B -> 4 blocks/CU
  __shared__ __align__(16) unsigned char RAW[34816];
  bf16* Ksb = (bf16*)RAW;             // 2 slots x 4096 bf16; slot(key,c^S(key))
  bf16* Vsb = (bf16*)(RAW + 16384);   // 2 slots x 4096 bf16; straight %8 pre-tiled
  ull*  Msb = (ull*)(RAW + 32768);    // [2 buf][64 rows * 2 parity]

  const int tid = threadIdx.x, lane = tid & 63, w = tid >> 6;
  const int hi = lane >> 5, l31 = lane & 31;
  const int kh = w & 1, qq = w >> 1;
  const int keyq = kh * 32 + l31;
  const int swz = (keyq ^ (keyq >> 3)) & 7;
  const int vo0 = ((kh * 4 + hi) * 64 + l31) * 8;  // ks2=0, d=l31
  const int vo1 = vo0 + 256;                        // ks2=0, d=l31+32
  const int vo2 = vo0 + 1024;                       // ks2=1, d=l31
  const int vo3 = vo2 + 256;                        // ks2=1, d=l31+32

  // Q frags (B-operand: col=q=l31, k=d=ks*16+hi*8+j) straight from global
  bf16x8 qf[4];
  {
    const bf16* qrow = Q + (size_t)(q0 + qq * 32 + l31) * 64 + hi * 8;
    qf[0] = *(const bf16x8*)(qrow);
    qf[1] = *(const bf16x8*)(qrow + 16);
    qf[2] = *(const bf16x8*)(qrow + 32);
    qf[3] = *(const bf16x8*)(qrow + 48);
  }

#define STAGE(T, SL)                                                            \
  {                                                                             \
    _Pragma("unroll")                                                           \
    for (int i_ = 0; i_ < 2; ++i_) {                                            \
      int s_ = tid + i_ * 256;                                                  \
      int key_ = s_ >> 3, c_ = (s_ & 7) ^ ((key_ ^ (key_ >> 3)) & 7);           \
      GLOAD16(K + ((size_t)(T) * 64 + key_) * 64 + c_ * 8, Ksb + (SL) * 4096 + s_ * 8); \
      GLOAD16(Vt + (size_t)(T) * 4096 + s_ * 8, Vsb + (SL) * 4096 + s_ * 8);    \
    }                                                                           \
  }

  // initial staging: kt=0 K/V, mask word pair (0,1) into buf 0
  STAGE(0, 0);
  if (w == 0) GLOAD16(mrow + (size_t)(q0 + lane) * 32, (bf16*)Msb + lane * 8);
  __syncthreads();

  f32x16 accO0 = {}, accO1 = {}, accL = {};
  const s16x8 one8s = {0x3F80, 0x3F80, 0x3F80, 0x3F80, 0x3F80, 0x3F80, 0x3F80, 0x3F80};
  const bf16x8 ones8 = __builtin_bit_cast(bf16x8, one8s);

  for (int kt = 0; kt < 32; ++kt) {
    const int cur = kt & 1;
    // prefetch next K/V (+mask every other kt) into the other buffers
    if (kt + 1 < 32) {
      STAGE(kt + 1, cur ^ 1);
      if ((kt & 1) && w == 0)
        GLOAD16(mrow + (size_t)(q0 + lane) * 32 + (kt + 1),
                (bf16*)Msb + (((kt + 1) >> 1) & 1) * 512 + lane * 8);
    }
    const ull word = Msb[((kt >> 1) & 1) * 128 + (qq * 32 + l31) * 2 + cur];
    flash_step(Ksb + cur * 4096, Vsb + cur * 4096, word, qf, ones8, hi, keyq, swz,
               vo0, vo1, vo2, vo3, accO0, accO1, accL);
    __syncthreads();
  }
#undef STAGE

  // epilogue: combine kh halves through reused LDS, then normalize + store
  float* red  = (float*)RAW;             // [qq][32 q][64 d] = 16 KB
  float* redL = (float*)(RAW + 16384);   // [qq][32 q] = 256 B
  if (kh == 1) {
#pragma unroll
    for (int r = 0; r < 16; ++r) {
      const int qrel = (r & 3) + 8 * (r >> 2) + 4 * hi;
      red[qq * 2048 + qrel * 64 + l31]      = accO0[r];
      red[qq * 2048 + qrel * 64 + 32 + l31] = accO1[r];
      if (l31 == 0) redL[qq * 32 + qrel] = accL[r];
    }
  }
  __syncthreads();
  if (kh == 0) {
#pragma unroll
    for (int r = 0; r < 16; ++r) {
      const int qrel = (r & 3) + 8 * (r >> 2) + 4 * hi;
      const float ls = accL[r] + redL[qq * 32 + qrel];
      const float rl = 1.0f / ls;
      const float o0 = accO0[r] + red[qq * 2048 + qrel * 64 + l31];
      const float o1 = accO1[r] + red[qq * 2048 + qrel * 64 + 32 + l31];
      const int rowg = q0 + qq * 32 + qrel;
      ctx[((size_t)b * L_ + rowg) * 1024 + h * 64 + l31]      = (bf16)(o0 * rl);
      ctx[((size_t)b * L_ + rowg) * 1024 + h * 64 + 32 + l31] = (bf16)(o1 * rl);
    }
  }
}

extern "C" void kernel_launch(void* const* d_in, const int* in_sizes, int n_in,
                              void* d_out, int out_size, void* d_ws, size_t ws_size,
                              hipStream_t stream) {
  (void)in_sizes; (void)n_in; (void)out_size; (void)ws_size;
  const float* q    = (const float*)d_in[0];
  const float* k    = (const float*)d_in[1];
  const float* v    = (const float*)d_in[2];
  const int*   mask = (const int*)d_in[3];
  const float* Wq = (const float*)d_in[4];
  const float* bq = (const float*)d_in[5];
  const float* Wk = (const float*)d_in[6];
  const float* bk = (const float*)d_in[7];
  const float* Wv = (const float*)d_in[8];
  const float* bv = (const float*)d_in[9];
  const float* Wo = (const float*)d_in[10];
  const float* bo = (const float*)d_in[11];
  float* out = (float*)d_out;

  char* ws = (char*)d_ws;
  const size_t SX = (size_t)4096 * 1024 * 2;  // 8 MB
  const size_t SW = (size_t)1024 * 1024 * 2;  // 2 MB
  bf16* X   = (bf16*)(ws);                    // Xq|Xk|Xv
  bf16* Wt  = (bf16*)(ws + 3 * SX);           // Wqt|Wkt|Wvt|Wot
  bf16* QKV = (bf16*)(ws + 3 * SX + 4 * SW);  // Qp|Kp|Vt(pre-tiled)
  bf16* Qp  = QKV;
  bf16* Kp  = QKV + 4194304;
  bf16* Vtp = QKV + 2 * 4194304;
  bf16* Ctx = (bf16*)(ws + 6 * SX + 4 * SW);
  ull* mbits = (ull*)(ws + 7 * SX + 4 * SW);

  dim3 blk(256);
  k_prep<<<5120, blk, 0, stream>>>(q, k, v, mask, Wq, Wk, Wv, Wo, X, Wt, mbits);

  k_gemm3<<<dim3(8, 32, 3), blk, 0, stream>>>(X, Wt, bq, bk, bv, QKV);

  k_flash<<<dim3(32, NH_, B_), blk, 0, stream>>>(Qp, Kp, Vtp, mbits, Ctx);

  k_gemmo<<<dim3(8, 64), blk, 0, stream>>>(Ctx, Wt + 3 * 1048576, bo, out);
}

// Round 6
// 256.530 us; speedup vs baseline: 1.0922x; 1.0389x over previous
//
#include <hip/hip_runtime.h>
#include <stdint.h>

typedef __bf16 bf16;
typedef __bf16 bf16x8 __attribute__((ext_vector_type(8)));
typedef __bf16 bf16x4 __attribute__((ext_vector_type(4)));
typedef __bf16 bf16x2 __attribute__((ext_vector_type(2)));
typedef float  f32x4  __attribute__((ext_vector_type(4)));
typedef float  f32x16 __attribute__((ext_vector_type(16)));
typedef short  s16x4  __attribute__((ext_vector_type(4)));
typedef short  s16x8  __attribute__((ext_vector_type(8)));
typedef unsigned int u32x2 __attribute__((ext_vector_type(2)));
typedef unsigned int u32x4 __attribute__((ext_vector_type(4)));
typedef unsigned long long ull;

#define GLOAD16(gptr, lptr)                                                     \
  __builtin_amdgcn_global_load_lds(                                             \
      (const __attribute__((address_space(1))) void*)(gptr),                    \
      (__attribute__((address_space(3))) void*)(lptr), 16, 0, 0)

#define MFMA16(a, b, c) __builtin_amdgcn_mfma_f32_16x16x32_bf16((a), (b), (c), 0, 0, 0)
#define MFMA32(a, b, c) __builtin_amdgcn_mfma_f32_32x32x16_bf16((a), (b), (c), 0, 0, 0)

static constexpr int B_ = 2, L_ = 2048, NH_ = 16, DH_ = 64;
static constexpr float QSCALE = 0.18033688011112042f;  // 0.125 * log2(e)

// ---------- fused prep (grid-stride, 5120 blocks): maskbits | cvt | transpose ----------
__global__ __launch_bounds__(256) void k_prep(const float* __restrict__ q,
                                              const float* __restrict__ k,
                                              const float* __restrict__ v,
                                              const int* __restrict__ mask,
                                              const float* __restrict__ wq,
                                              const float* __restrict__ wk,
                                              const float* __restrict__ wv,
                                              const float* __restrict__ wo,
                                              bf16* __restrict__ X,
                                              bf16* __restrict__ Wt,
                                              ull* __restrict__ mb) {
  __shared__ float t[32][33];
  const int bid = blockIdx.x, tid = threadIdx.x;
  if (bid < 2048) {  // mask int32 -> packed bits: 16 chunks/block
#pragma unroll
    for (int it = 0; it < 16; ++it) {
      int tt = (bid * 16 + it) * 256 + tid;
      ull bal = __ballot(mask[tt] != 0);
      if ((tid & 63) == 0) mb[tt >> 6] = bal;
    }
  } else if (bid < 4096) {  // fp32 -> bf16 x4: 6 chunks/block
    const int u0 = (bid - 2048) * 6;
#pragma unroll
    for (int it = 0; it < 6; ++it) {
      int u = u0 + it;
      int z = u >> 12, x = u & 4095;
      const float* in = z == 0 ? q : (z == 1 ? k : v);
      bf16* out = X + (size_t)z * 4194304;
      int i = x * 256 + tid;
      const float4 f = ((const float4*)in)[i];
      bf16x4 o = {(bf16)f.x, (bf16)f.y, (bf16)f.z, (bf16)f.w};
      ((bf16x4*)out)[i] = o;
    }
  } else {  // weight fp32 KxN -> bf16 NxK: 4 tiles/block
    const int t0 = (bid - 4096) * 4;
    for (int it = 0; it < 4; ++it) {
      int u = t0 + it;
      int z = u >> 10, rem = u & 1023;
      const float* in = z == 0 ? wq : (z == 1 ? wk : (z == 2 ? wv : wo));
      bf16* out = Wt + (size_t)z * 1048576;
      int bx = (rem & 31) * 32, by = (rem >> 5) * 32;
      int x = tid & 31, y = tid >> 5;
#pragma unroll
      for (int r = 0; r < 4; ++r)
        t[y + r * 8][x] = in[(size_t)(by + y + r * 8) * 1024 + bx + x];
      __syncthreads();
#pragma unroll
      for (int r = 0; r < 4; ++r)
        out[(size_t)(bx + y + r * 8) * 1024 + by + x] = (bf16)t[x][y + r * 8];
      __syncthreads();  // WAR on t before next tile
    }
  }
}

// ---------- batched 3-proj GEMM: 128x128 tile, BK=32 (m97 structure) ----------
// 1D grid 768 with XCD-chunked decode: the 8 n-tiles sharing one A-panel get
// linear ids == c (mod 8) -> same XCD -> A-panel lives in ONE L2 (T1).
// z=0: Q scaled by QSCALE. z=2: V pre-tiled per raw-view head (faithful-bug reshape),
//   %8 key-grouping: h = l>>7, i = (l&127)*16 + (col>>6), d = col&63;
//   Vt[bh][((i>>3)*64 + d)*8 + (i&7)]  (one 16B b128 frag per PV B-operand in k_flash)
__global__ __launch_bounds__(256) void k_gemm3(const bf16* __restrict__ Xb,
                                               const bf16* __restrict__ Wb,
                                               const float* __restrict__ b0,
                                               const float* __restrict__ b1,
                                               const float* __restrict__ b2,
                                               bf16* __restrict__ Ob) {
  const int lin = blockIdx.x;
  const int cx = lin & 7, j = (lin >> 3) & 7, gg = lin >> 6;
  const int g = gg * 8 + cx;      // panel group 0..95
  const int y = g & 31, z = g >> 5;
  const int m0 = y * 128, n0 = j * 128;
  const bf16* A  = Xb + (size_t)z * 4194304;
  const bf16* Bt = Wb + (size_t)z * 1048576;
  const float* bias = z == 0 ? b0 : (z == 1 ? b1 : b2);
  bf16* C = Ob + (size_t)z * 4194304;
  __shared__ __align__(16) bf16 As[128 * 32];  // slot(r,c) = r*4 + (c ^ ((r>>1)&3))
  __shared__ __align__(16) bf16 Bs[128 * 32];
  const int tid = threadIdx.x, lane = tid & 63, w = tid >> 6, quad = lane >> 4, l15 = lane & 15;
  const int wm = (w & 1) * 64, wn = (w >> 1) * 64;
  f32x4 acc[4][4] = {};
  for (int kt = 0; kt < 32; ++kt) {
    const int kk = kt * 32;
#pragma unroll
    for (int i = 0; i < 2; ++i) {
      int s = tid + i * 256;
      int r = s >> 2, c = (s & 3) ^ ((r >> 1) & 3);
      GLOAD16(A + (size_t)(m0 + r) * 1024 + kk + c * 8, As + s * 8);
      GLOAD16(Bt + (size_t)(n0 + r) * 1024 + kk + c * 8, Bs + s * 8);
    }
    __syncthreads();
    bf16x8 af[4], bb[4];
#pragma unroll
    for (int i = 0; i < 4; ++i) {
      int ra = wm + i * 16 + l15, rb = wn + i * 16 + l15;
      af[i] = *(const bf16x8*)(As + (ra * 4 + (quad ^ ((ra >> 1) & 3))) * 8);
      bb[i] = *(const bf16x8*)(Bs + (rb * 4 + (quad ^ ((rb >> 1) & 3))) * 8);
    }
#pragma unroll
    for (int mi = 0; mi < 4; ++mi)
#pragma unroll
      for (int ni = 0; ni < 4; ++ni)
        acc[mi][ni] = MFMA16(af[mi], bb[ni], acc[mi][ni]);
    __syncthreads();
  }
  const float scale = (z == 0) ? QSCALE : 1.0f;
#pragma unroll
  for (int mi = 0; mi < 4; ++mi)
#pragma unroll
    for (int ni = 0; ni < 4; ++ni) {
      int row = m0 + wm + mi * 16 + quad * 4;
      int col = n0 + wn + ni * 16 + l15;
      float bz = bias[col];
      if (z == 2) {
        int b_ = row >> 11, l = row & 2047;
        int hh = l >> 7;
        int i0 = (l & 127) * 16 + (col >> 6);
        int d  = col & 63;
        bf16* dst = C + (size_t)(b_ * 16 + hh) * 131072;
#pragma unroll
        for (int r = 0; r < 4; ++r) {
          int iK = i0 + 16 * r;
          dst[((size_t)(iK >> 3) * 64 + d) * 8 + (iK & 7)] = (bf16)(acc[mi][ni][r] + bz);
        }
      } else {
#pragma unroll
        for (int r = 0; r < 4; ++r)
          C[(size_t)(row + r) * 1024 + col] = (bf16)((acc[mi][ni][r] + bz) * scale);
      }
    }
}

// ---------- output GEMM: 64x128 tile, fp32 out + bias (m97 structure) ----------
// Same XCD-chunked 1D decode (512 blocks).
__global__ __launch_bounds__(256) void k_gemmo(const bf16* __restrict__ A,
                                               const bf16* __restrict__ Bt,
                                               const float* __restrict__ bias,
                                               float* __restrict__ C) {
  const int lin = blockIdx.x;
  const int cx = lin & 7, j = (lin >> 3) & 7, gg = lin >> 6;
  const int y = gg * 8 + cx;      // 0..63
  const int m0 = y * 64, n0 = j * 128;
  __shared__ __align__(16) bf16 As[64 * 32];
  __shared__ __align__(16) bf16 Bs[128 * 32];
  const int tid = threadIdx.x, lane = tid & 63, w = tid >> 6, quad = lane >> 4, l15 = lane & 15;
  const int wn = w * 32;
  f32x4 acc[4][2] = {};
  for (int kt = 0; kt < 32; ++kt) {
    const int kk = kt * 32;
    {
      int r = tid >> 2, c = (tid & 3) ^ ((r >> 1) & 3);
      GLOAD16(A + (size_t)(m0 + r) * 1024 + kk + c * 8, As + tid * 8);
    }
#pragma unroll
    for (int i = 0; i < 2; ++i) {
      int s = tid + i * 256;
      int r = s >> 2, c = (s & 3) ^ ((r >> 1) & 3);
      GLOAD16(Bt + (size_t)(n0 + r) * 1024 + kk + c * 8, Bs + s * 8);
    }
    __syncthreads();
    bf16x8 af[4], bb[2];
#pragma unroll
    for (int i = 0; i < 4; ++i) {
      int ra = i * 16 + l15;
      af[i] = *(const bf16x8*)(As + (ra * 4 + (quad ^ ((ra >> 1) & 3))) * 8);
    }
#pragma unroll
    for (int i = 0; i < 2; ++i) {
      int rb = wn + i * 16 + l15;
      bb[i] = *(const bf16x8*)(Bs + (rb * 4 + (quad ^ ((rb >> 1) & 3))) * 8);
    }
#pragma unroll
    for (int mi = 0; mi < 4; ++mi)
#pragma unroll
      for (int ni = 0; ni < 2; ++ni)
        acc[mi][ni] = MFMA16(af[mi], bb[ni], acc[mi][ni]);
    __syncthreads();
  }
#pragma unroll
  for (int mi = 0; mi < 4; ++mi)
#pragma unroll
    for (int ni = 0; ni < 2; ++ni) {
      int row = m0 + mi * 16 + quad * 4;
      int col = n0 + wn + ni * 16 + l15;
      float bz = bias[col];
#pragma unroll
      for (int r = 0; r < 4; ++r)
        C[(size_t)(row + r) * 1024 + col] = acc[mi][ni][r] + bz;
    }
}

static __device__ __forceinline__ unsigned pack2(float a, float b) {
  bf16x2 t = {(bf16)a, (bf16)b};
  return __builtin_bit_cast(unsigned, t);
}

// One kt step: K (swizzled) and V (%8 pre-tiled, single b128) from LDS;
// mask bits for this lane's kh-half already isolated in mw32.
static __device__ __forceinline__ void flash_step(
    const bf16* __restrict__ Kc, const bf16* __restrict__ Vc, unsigned mw32,
    const bf16x8 (&qf)[4], bf16x8 ones8,
    int hi, int keyq, int swz, int vo0, int vo1, int vo2, int vo3,
    f32x16& accO0, f32x16& accO1, f32x16& accL) {
  // V frags: single b128 LDS reads (conflict-free: 16B/lane consecutive)
  bf16x8 v0 = *(const bf16x8*)(Vc + vo0);
  bf16x8 v1 = *(const bf16x8*)(Vc + vo1);
  bf16x8 v2 = *(const bf16x8*)(Vc + vo2);
  bf16x8 v3 = *(const bf16x8*)(Vc + vo3);

  // St = K Q^T (C: col=q, row=key_rel=(reg&3)+8*(reg>>2)+4*hi)
  f32x16 st = {};
  __builtin_amdgcn_s_setprio(1);
#pragma unroll
  for (int ks = 0; ks < 4; ++ks) {
    bf16x8 kf = *(const bf16x8*)(Kc + (keyq * 8 + ((ks * 2 + hi) ^ swz)) * 8);
    st = MFMA32(kf, qf[ks], st);
  }
  __builtin_amdgcn_s_setprio(0);

  // mask + exp2
#pragma unroll
  for (int r = 0; r < 16; ++r) {
    const int bit = (r >> 2) * 8 + (r & 3);
    st[r] = (mw32 >> bit) & 1u ? __builtin_amdgcn_exp2f(st[r]) : 0.f;
  }

  // pack P pairs + permlane32_swap -> PV A-frags (k = hi*8 + j)
  bf16x8 af0, af1;
  {
    unsigned c0 = pack2(st[0], st[1]);
    unsigned c1 = pack2(st[2], st[3]);
    unsigned c2 = pack2(st[4], st[5]);
    unsigned c3 = pack2(st[6], st[7]);
    u32x2 s0 = __builtin_amdgcn_permlane32_swap(c0, c2, false, false);
    u32x2 s1 = __builtin_amdgcn_permlane32_swap(c1, c3, false, false);
    u32x4 a4 = {s0.x, s1.x, s0.y, s1.y};
    af0 = __builtin_bit_cast(bf16x8, a4);
    c0 = pack2(st[8], st[9]);
    c1 = pack2(st[10], st[11]);
    c2 = pack2(st[12], st[13]);
    c3 = pack2(st[14], st[15]);
    s0 = __builtin_amdgcn_permlane32_swap(c0, c2, false, false);
    s1 = __builtin_amdgcn_permlane32_swap(c1, c3, false, false);
    u32x4 b4 = {s0.x, s1.x, s0.y, s1.y};
    af1 = __builtin_bit_cast(bf16x8, b4);
  }

  __builtin_amdgcn_s_setprio(1);
  accL  = MFMA32(af0, ones8, accL);
  accL  = MFMA32(af1, ones8, accL);
  accO0 = MFMA32(af0, v0, accO0);
  accO1 = MFMA32(af0, v1, accO1);
  accO0 = MFMA32(af1, v2, accO0);
  accO1 = MFMA32(af1, v3, accO1);
  __builtin_amdgcn_s_setprio(0);
}

// ---------- flash attention: R2 structure (best measured) + conflict-free K swizzle ----------
// 512 thr = 8 waves = (key-half kh x q-quarter qq); q-tile 128; grid 512 blocks.
// K,V,mask LDS double-buffered, one __syncthreads per kt (proven best schedule).
// K swizzle S(key)=(key^(key>>3))&7 kills the 4-way bank conflict between lanes
// with equal key&7 (R5-measured: conflicts 2.1M -> 262K).
__global__ __launch_bounds__(512) void k_flash(const bf16* __restrict__ Qp,
                                               const bf16* __restrict__ Kp,
                                               const bf16* __restrict__ Vtp,
                                               const ull* __restrict__ mb,
                                               bf16* __restrict__ ctx) {
  const int b = blockIdx.z, h = blockIdx.y, q0 = blockIdx.x * 128;
  const size_t HEAD = 131072;
  const bf16* Q  = Qp  + ((size_t)b * NH_ + h) * HEAD;  // pre-scaled by QSCALE
  const bf16* K  = Kp  + ((size_t)b * NH_ + h) * HEAD;  // row-major [key][d]
  const bf16* Vt = Vtp + ((size_t)b * NH_ + h) * HEAD;  // pre-tiled [key>>3][d][key&7]
  const ull* mrow = mb + (size_t)b * L_ * 32;

  // LDS: Ks 2x8KB | Vs 2x8KB | Ms 2x2KB = 36864 B
  __shared__ __align__(16) unsigned char RAW[36864];
  bf16* Ksb = (bf16*)RAW;             // 2 slots x 4096; slot(key, c ^ S(key))
  bf16* Vsb = (bf16*)(RAW + 16384);   // 2 slots x 4096; straight %8 pre-tiled
  ull*  Msb = (ull*)(RAW + 32768);    // [2 buf][row*2 + parity]
  const unsigned* Ms32 = (const unsigned*)(RAW + 32768);

  const int tid = threadIdx.x, lane = tid & 63, w = tid >> 6;
  const int hi = lane >> 5, l31 = lane & 31;
  const int kh = w & 1, qq = w >> 1;
  const int keyq = kh * 32 + l31;
  const int swz = (keyq ^ (keyq >> 3)) & 7;
  const int vo0 = ((kh * 4 + hi) * 64 + l31) * 8;  // ks2=0, d=l31
  const int vo1 = vo0 + 256;                        // ks2=0, d=l31+32
  const int vo2 = vo0 + 1024;                       // ks2=1, d=l31
  const int vo3 = vo2 + 256;                        // ks2=1, d=l31+32

  // Q frags (B-operand: col=q=l31, k=d=ks*16+hi*8+j) straight from global
  bf16x8 qf[4];
  {
    const bf16* qrow = Q + (size_t)(q0 + qq * 32 + l31) * 64 + hi * 8;
    qf[0] = *(const bf16x8*)(qrow);
    qf[1] = *(const bf16x8*)(qrow + 16);
    qf[2] = *(const bf16x8*)(qrow + 32);
    qf[3] = *(const bf16x8*)(qrow + 48);
  }

#define STAGE(T, SL)                                                            \
  {                                                                             \
    int s_ = tid, key_ = s_ >> 3, c_ = (s_ & 7) ^ ((key_ ^ (key_ >> 3)) & 7);   \
    GLOAD16(K + ((size_t)(T) * 64 + key_) * 64 + c_ * 8, Ksb + (SL) * 4096 + s_ * 8); \
    GLOAD16(Vt + (size_t)(T) * 4096 + s_ * 8, Vsb + (SL) * 4096 + s_ * 8);      \
  }

  // initial staging: kt=0 K/V, mask word pair (0,1) into buf 0
  STAGE(0, 0);
  if (w < 2) {
    int r = w * 64 + lane;
    GLOAD16(mrow + (size_t)(q0 + r) * 32, (bf16*)Msb + r * 8);
  }
  __syncthreads();

  f32x16 accO0 = {}, accO1 = {}, accL = {};
  const s16x8 one8s = {0x3F80, 0x3F80, 0x3F80, 0x3F80, 0x3F80, 0x3F80, 0x3F80, 0x3F80};
  const bf16x8 ones8 = __builtin_bit_cast(bf16x8, one8s);

  for (int kt = 0; kt < 32; ++kt) {
    const int cur = kt & 1;
    // prefetch next K/V (+mask every other kt) into the other buffers
    if (kt + 1 < 32) {
      STAGE(kt + 1, cur ^ 1);
      if ((kt & 1) && w < 2) {
        int r = w * 64 + lane;
        GLOAD16(mrow + (size_t)(q0 + r) * 32 + (kt + 1),
                (bf16*)Msb + (((kt + 1) >> 1) & 1) * 1024 + r * 8);
      }
    }
    // this lane's 32 mask bits (kh-half of the 64-bit word), u32 access
    const unsigned mw32 =
        Ms32[((((kt >> 1) & 1) * 256 + (qq * 32 + l31) * 2 + cur) << 1) + kh] >> (4 * hi);
    flash_step(Ksb + cur * 4096, Vsb + cur * 4096, mw32, qf, ones8, hi, keyq, swz,
               vo0, vo1, vo2, vo3, accO0, accO1, accL);
    __syncthreads();
  }
#undef STAGE

  // epilogue: combine kh halves through reused LDS, then normalize + store
  float* red  = (float*)RAW;            // [qq][32 q][64 d] = 32 KB
  float* redL = (float*)(RAW + 32768);  // [qq][32 q] = 512 B
  if (kh == 1) {
#pragma unroll
    for (int r = 0; r < 16; ++r) {
      const int qrel = (r & 3) + 8 * (r >> 2) + 4 * hi;
      red[qq * 2048 + qrel * 64 + l31]      = accO0[r];
      red[qq * 2048 + qrel * 64 + 32 + l31] = accO1[r];
      if (l31 == 0) redL[qq * 32 + qrel] = accL[r];
    }
  }
  __syncthreads();
  if (kh == 0) {
#pragma unroll
    for (int r = 0; r < 16; ++r) {
      const int qrel = (r & 3) + 8 * (r >> 2) + 4 * hi;
      const float ls = accL[r] + redL[qq * 32 + qrel];
      const float rl = 1.0f / ls;
      const float o0 = accO0[r] + red[qq * 2048 + qrel * 64 + l31];
      const float o1 = accO1[r] + red[qq * 2048 + qrel * 64 + 32 + l31];
      const int rowg = q0 + qq * 32 + qrel;
      ctx[((size_t)b * L_ + rowg) * 1024 + h * 64 + l31]      = (bf16)(o0 * rl);
      ctx[((size_t)b * L_ + rowg) * 1024 + h * 64 + 32 + l31] = (bf16)(o1 * rl);
    }
  }
}

extern "C" void kernel_launch(void* const* d_in, const int* in_sizes, int n_in,
                              void* d_out, int out_size, void* d_ws, size_t ws_size,
                              hipStream_t stream) {
  (void)in_sizes; (void)n_in; (void)out_size; (void)ws_size;
  const float* q    = (const float*)d_in[0];
  const float* k    = (const float*)d_in[1];
  const float* v    = (const float*)d_in[2];
  const int*   mask = (const int*)d_in[3];
  const float* Wq = (const float*)d_in[4];
  const float* bq = (const float*)d_in[5];
  const float* Wk = (const float*)d_in[6];
  const float* bk = (const float*)d_in[7];
  const float* Wv = (const float*)d_in[8];
  const float* bv = (const float*)d_in[9];
  const float* Wo = (const float*)d_in[10];
  const float* bo = (const float*)d_in[11];
  float* out = (float*)d_out;

  char* ws = (char*)d_ws;
  const size_t SX = (size_t)4096 * 1024 * 2;  // 8 MB
  const size_t SW = (size_t)1024 * 1024 * 2;  // 2 MB
  bf16* X   = (bf16*)(ws);                    // Xq|Xk|Xv
  bf16* Wt  = (bf16*)(ws + 3 * SX);           // Wqt|Wkt|Wvt|Wot
  bf16* QKV = (bf16*)(ws + 3 * SX + 4 * SW);  // Qp|Kp|Vt(pre-tiled)
  bf16* Qp  = QKV;
  bf16* Kp  = QKV + 4194304;
  bf16* Vtp = QKV + 2 * 4194304;
  bf16* Ctx = (bf16*)(ws + 6 * SX + 4 * SW);
  ull* mbits = (ull*)(ws + 7 * SX + 4 * SW);

  dim3 blk(256);
  k_prep<<<5120, blk, 0, stream>>>(q, k, v, mask, Wq, Wk, Wv, Wo, X, Wt, mbits);

  k_gemm3<<<768, blk, 0, stream>>>(X, Wt, bq, bk, bv, QKV);

  k_flash<<<dim3(16, NH_, B_), dim3(512), 0, stream>>>(Qp, Kp, Vtp, mbits, Ctx);

  k_gemmo<<<512, blk, 0, stream>>>(Ctx, Wt + 3 * 1048576, bo, out);
}